// Round 6
// baseline (48.419 us; speedup 1.0000x reference)
//
#include <hip/hip_runtime.h>

#define B_MOL 64
#define MAXN 28
#define NSPEC 4
#define NRS2 24
#define NRS3 20
#define NPAIR 10
#define NCOMB 378                       // 28*27/2 fixed (j<k) combos
#define REP2_LEN (NSPEC * NRS2)         // 96
#define REP3_LEN (NPAIR * NRS3 * 2)     // 400
#define OUT_LEN (REP2_LEN + REP3_LEN)   // 496
#define NBIN3 (NPAIR * NRS3)            // 200 gather bins
#define RCUT 8.0f
#define ETA2 0.32f
#define ETA3 2.7f
#define LOG2E 1.4426950408889634f
#define LN2F 0.6931471805599453f
// sqrt(2.7/pi)*13.4 computed in double, cast to f32
#define W3 12.4225783348083f

// hardware transcendentals (raw gfx950 instructions, no libm namespace)
__device__ __forceinline__ float hexp2(float x) { return __builtin_amdgcn_exp2f(x); }
__device__ __forceinline__ float hlog2(float x) { return __builtin_amdgcn_logf(x); }
__device__ __forceinline__ float hrcp(float x)  { return __builtin_amdgcn_rcpf(x); }
__device__ __forceinline__ float hrsq(float x)  { return __builtin_amdgcn_rsqf(x); }
// cos(2*pi*t), t in revolutions
__device__ __forceinline__ float hcos_rev(float t) { return __builtin_amdgcn_cosf(t); }

// compile-time (j,k) pair table, j<k<28, packed (j<<8)|k
struct PairTab { unsigned short jk[NCOMB]; };
static constexpr PairTab make_tab() {
    PairTab t{};
    int idx = 0;
    for (int j = 0; j < MAXN; ++j)
        for (int k = j + 1; k < MAXN; ++k)
            t.jk[idx++] = (unsigned short)((j << 8) | k);
    return t;
}
__constant__ PairTab PT = make_tab();

__global__ __launch_bounds__(256) void fchl_kernel(
    const float* __restrict__ X,      // [B][MAXN][3]
    const float* __restrict__ Z,      // [B][MAXN]
    const int* __restrict__ counts,   // [B]
    float* __restrict__ out)          // [B][MAXN][OUT_LEN]
{
    const int i = blockIdx.x;      // atom index within molecule
    const int b = blockIdx.y;      // molecule
    const int tid = threadIdx.x;
    const int cnt = counts[b];

    __shared__ float sx[MAXN], sy[MAXN], szc[MAXN];
    __shared__ int   s_win[MAXN];
    __shared__ float s_r[MAXN], s_fc[MAXN], s_mu[MAXN], s_i2ln[MAXN], s_pref[MAXN];
    __shared__ int   sspec[MAXN];
    __shared__ int   cntP[NPAIR], curP[NPAIR];
    __shared__ int   cntSp[NSPEC];
    __shared__ int   spList[NSPEC][MAXN];
    __shared__ float4 s_pair[NCOMB];

    float* orow = out + (size_t)(b * MAXN + i) * OUT_LEN;

    // ---- P1: zero counters + per-neighbor-j quantities + species lists ----
    if (tid >= 28 && tid < 28 + NSPEC) cntSp[tid - 28] = 0;        // wave 0, stmt before the atomics below
    if (tid >= 64 && tid < 64 + NPAIR) { cntP[tid - 64] = 0; curP[tid - 64] = 0; }  // wave 1
    if (tid < MAXN) {
        const int j = tid;
        float xi = X[(b * MAXN + i) * 3 + 0];   // broadcast loads
        float yi = X[(b * MAXN + i) * 3 + 1];
        float zi = X[(b * MAXN + i) * 3 + 2];
        float xj = X[(b * MAXN + j) * 3 + 0];
        float yj = X[(b * MAXN + j) * 3 + 1];
        float zj = X[(b * MAXN + j) * 3 + 2];
        sx[j] = xj; sy[j] = yj; szc[j] = zj;
        float z = Z[b * MAXN + j];
        int s = -1;
        if (z == 1.0f) s = 0;
        else if (z == 6.0f) s = 1;
        else if (z == 7.0f) s = 2;
        else if (z == 8.0f) s = 3;
        sspec[j] = s;

        float dx = xi - xj, dy = yi - yj, dz = zi - zj;
        float r = sqrtf(dx * dx + dy * dy + dz * dz);
        bool w = (i < cnt) && (j < cnt) && (j != i) && (r < RCUT);
        s_win[j] = w ? 1 : 0;
        if (w) {
            // fc = 0.5*(cos(pi*r/8)+1) = 0.5*(cos(2pi * r/16)+1)
            float fc = 0.5f * (hcos_rev(r * (1.0f / 16.0f)) + 1.0f);
            float ln = LN2F * hlog2(1.0f + ETA2 * hrcp(r * r));
            float lr = LN2F * hlog2(r);
            s_r[j] = r;
            s_fc[j] = fc;
            s_mu[j] = lr - 0.5f * ln;
            s_i2ln[j] = LOG2E / (2.0f * ln);
            s_pref[j] = fc * hexp2(-1.8f * hlog2(r)) * hrsq(ln);  // fc*r^-1.8/sqrt(ln)
            int pos = atomicAdd(&cntSp[s], 1);
            spList[s][pos] = j;
        } else {
            s_r[j] = 1.0f; s_fc[j] = 0.0f; s_mu[j] = 0.0f;
            s_i2ln[j] = 1.0f; s_pref[j] = 0.0f;
        }
    }
    __syncthreads();   // bar A

    // ---- P2: fused histogram + geometry into registers (<=2 combos/thread) ----
    float av0 = 0.f, a00 = 0.f, a10 = 0.f; int tg0 = -1;
    float av1 = 0.f, a01 = 0.f, a11 = 0.f; int tg1 = -1;
    {
        int jk = PT.jk[tid];                       // idx = tid (0..255, always < 378)
        int j = jk >> 8, k = jk & 255;
        if (s_win[j] && s_win[k]) {
            float rij = s_r[j], rik = s_r[k];
            float dx = sx[j] - sx[k], dy = sy[j] - sy[k], dz = szc[j] - szc[k];
            float rjk = sqrtf(dx * dx + dy * dy + dz * dz);
            float rij2 = rij * rij, rik2 = rik * rik, rjk2 = rjk * rjk;
            float cos_i = (rij2 + rik2 - rjk2) * 0.5f * hrcp(rij * rik);
            float cos_j = (rij2 + rjk2 - rik2) * 0.5f * hrcp(rij * rjk);
            float cos_k = (rik2 + rjk2 - rij2) * 0.5f * hrcp(rik * rjk);
            float atm = (1.0f + 3.0f * cos_i * cos_j * cos_k)
                        * hexp2(-0.57f * hlog2(rij * rik * rjk));
            float w = W3 * atm * s_fc[j] * s_fc[k];
            float c = fminf(fmaxf(cos_i, -1.0f), 1.0f);
            float sn = sqrtf(fminf(fmaxf(1.0f - c * c, 1e-12f), 1.0f));
            int pj = sspec[j], pk = sspec[k];
            int pp = min(pj, pk), q = max(pj, pk);
            tg0 = pp * NSPEC - (pp * (pp - 1)) / 2 + (q - pp);
            atomicAdd(&cntP[tg0], 1);
            av0 = 0.5f * (rij + rik);
            a00 = 2.0f * c * w;
            a10 = 2.0f * sn * w;
        }
    }
    if (tid < NCOMB - 256) {                       // idx = tid+256 (122 threads, waves 0-1)
        int jk = PT.jk[tid + 256];
        int j = jk >> 8, k = jk & 255;
        if (s_win[j] && s_win[k]) {
            float rij = s_r[j], rik = s_r[k];
            float dx = sx[j] - sx[k], dy = sy[j] - sy[k], dz = szc[j] - szc[k];
            float rjk = sqrtf(dx * dx + dy * dy + dz * dz);
            float rij2 = rij * rij, rik2 = rik * rik, rjk2 = rjk * rjk;
            float cos_i = (rij2 + rik2 - rjk2) * 0.5f * hrcp(rij * rik);
            float cos_j = (rij2 + rjk2 - rik2) * 0.5f * hrcp(rij * rjk);
            float cos_k = (rik2 + rjk2 - rij2) * 0.5f * hrcp(rik * rjk);
            float atm = (1.0f + 3.0f * cos_i * cos_j * cos_k)
                        * hexp2(-0.57f * hlog2(rij * rik * rjk));
            float w = W3 * atm * s_fc[j] * s_fc[k];
            float c = fminf(fmaxf(cos_i, -1.0f), 1.0f);
            float sn = sqrtf(fminf(fmaxf(1.0f - c * c, 1e-12f), 1.0f));
            int pj = sspec[j], pk = sspec[k];
            int pp = min(pj, pk), q = max(pj, pk);
            tg1 = pp * NSPEC - (pp * (pp - 1)) / 2 + (q - pp);
            atomicAdd(&cntP[tg1], 1);
            av1 = 0.5f * (rij + rik);
            a01 = 2.0f * c * w;
            a11 = 2.0f * sn * w;
        }
    }
    __syncthreads();   // bar B

    // ---- P3: scatter register combos into P-sorted LDS ----
    if (tg0 >= 0) {
        int bs = 0;
        #pragma unroll
        for (int q = 0; q < NPAIR - 1; ++q) bs += (q < tg0) ? cntP[q] : 0;
        int slot = bs + atomicAdd(&curP[tg0], 1);
        s_pair[slot] = make_float4(av0, a00, a10, 0.0f);
    }
    if (tg1 >= 0) {
        int bs = 0;
        #pragma unroll
        for (int q = 0; q < NPAIR - 1; ++q) bs += (q < tg1) ? cntP[q] : 0;
        int slot = bs + atomicAdd(&curP[tg1], 1);
        s_pair[slot] = make_float4(av1, a01, a11, 0.0f);
    }
    __syncthreads();   // bar C

    // ---- P4: wave-homogeneous tail ----
    // round 1: tids 0-95 two-body (96-127 idle), tids 128-255 gather bins 0-127
    // round 2: tids 0-71 gather bins 128-199
    if (tid < 128) {
        if (tid < REP2_LEN) {
            const int sp = tid / NRS2;
            const int m = tid % NRS2;
            const float rs2 = (float)(m + 1) * (8.0f / 24.0f);
            const float lrs2 = LN2F * hlog2(rs2);
            const float nrm = 0.3989422804014327f / rs2;   // 1/(sqrt(2pi)*rs2)
            float acc = 0.0f;
            const int n = cntSp[sp];
            for (int c = 0; c < n; ++c) {
                int j = spList[sp][c];
                float d = lrs2 - s_mu[j];
                acc += s_pref[j] * hexp2(-d * d * s_i2ln[j]);
            }
            orow[sp * NRS2 + m] = acc * nrm;
        }
    } else {
        const int g = tid - 128;                   // bins 0..127
        const int P = g / NRS3;
        const int l = g % NRS3;
        const float rs = 0.4f * (float)(l + 1);
        int s0 = 0;
        #pragma unroll
        for (int q = 0; q < NPAIR - 1; ++q) s0 += (q < P) ? cntP[q] : 0;
        const int s1 = s0 + cntP[P];
        float acc0 = 0.0f, acc1 = 0.0f;
        float4 pd = (s0 < s1) ? s_pair[s0] : make_float4(0.f, 0.f, 0.f, 0.f);
        for (int s = s0; s < s1; ++s) {
            float4 nx = (s + 1 < s1) ? s_pair[s + 1] : pd;   // prefetch
            float dd = pd.x - rs;
            float e = hexp2(-(ETA3 * LOG2E) * dd * dd);
            acc0 += pd.y * e;
            acc1 += pd.z * e;
            pd = nx;
        }
        orow[REP2_LEN + P * (NRS3 * 2) + l * 2 + 0] = acc0;
        orow[REP2_LEN + P * (NRS3 * 2) + l * 2 + 1] = acc1;
    }
    if (tid < NBIN3 - 128) {                       // bins 128..199 on tids 0..71
        const int g = 128 + tid;
        const int P = g / NRS3;
        const int l = g % NRS3;
        const float rs = 0.4f * (float)(l + 1);
        int s0 = 0;
        #pragma unroll
        for (int q = 0; q < NPAIR - 1; ++q) s0 += (q < P) ? cntP[q] : 0;
        const int s1 = s0 + cntP[P];
        float acc0 = 0.0f, acc1 = 0.0f;
        float4 pd = (s0 < s1) ? s_pair[s0] : make_float4(0.f, 0.f, 0.f, 0.f);
        for (int s = s0; s < s1; ++s) {
            float4 nx = (s + 1 < s1) ? s_pair[s + 1] : pd;   // prefetch
            float dd = pd.x - rs;
            float e = hexp2(-(ETA3 * LOG2E) * dd * dd);
            acc0 += pd.y * e;
            acc1 += pd.z * e;
            pd = nx;
        }
        orow[REP2_LEN + P * (NRS3 * 2) + l * 2 + 0] = acc0;
        orow[REP2_LEN + P * (NRS3 * 2) + l * 2 + 1] = acc1;
    }
}

extern "C" void kernel_launch(void* const* d_in, const int* in_sizes, int n_in,
                              void* d_out, int out_size, void* d_ws, size_t ws_size,
                              hipStream_t stream) {
    const float* X = (const float*)d_in[0];
    const float* Z = (const float*)d_in[1];
    // d_in[2] = atomIDs, d_in[3] = molIDs (unused by reference math)
    const int* counts = (const int*)d_in[4];
    float* out = (float*)d_out;

    dim3 grid(MAXN, B_MOL);   // one block per (atom i, molecule b)
    dim3 block(256);
    hipLaunchKernelGGL(fchl_kernel, grid, block, 0, stream, X, Z, counts, out);
}

// Round 7
// 21.630 us; speedup vs baseline: 2.2386x; 2.2386x over previous
//
#include <hip/hip_runtime.h>

#define B_MOL 64
#define MAXN 28
#define NSPEC 4
#define NRS2 24
#define NRS3 20
#define NPAIR 10
#define NCOMB 378                       // 28*27/2 fixed (j<k) combos
#define REP2_LEN (NSPEC * NRS2)         // 96
#define REP3_LEN (NPAIR * NRS3 * 2)     // 400
#define OUT_LEN (REP2_LEN + REP3_LEN)   // 496 floats = 124 float4
#define NTASK (NPAIR * NRS3 + REP2_LEN) // 296 tail tasks
#define RCUT 8.0f
#define ETA2 0.32f
#define ETA3 2.7f
#define LOG2E 1.4426950408889634f
#define LN2F 0.6931471805599453f
// sqrt(2.7/pi)*13.4 computed in double, cast to f32
#define W3 12.4225783348083f

// hardware transcendentals (raw gfx950 instructions, no libm namespace)
__device__ __forceinline__ float hexp2(float x) { return __builtin_amdgcn_exp2f(x); }
__device__ __forceinline__ float hlog2(float x) { return __builtin_amdgcn_logf(x); }
__device__ __forceinline__ float hrcp(float x)  { return __builtin_amdgcn_rcpf(x); }
__device__ __forceinline__ float hrsq(float x)  { return __builtin_amdgcn_rsqf(x); }
// cos(2*pi*t), t in revolutions
__device__ __forceinline__ float hcos_rev(float t) { return __builtin_amdgcn_cosf(t); }

// compile-time (j,k) pair table, j<k<28, packed (j<<8)|k
struct PairTab { unsigned short jk[NCOMB]; };
static constexpr PairTab make_tab() {
    PairTab t{};
    int idx = 0;
    for (int j = 0; j < MAXN; ++j)
        for (int k = j + 1; k < MAXN; ++k)
            t.jk[idx++] = (unsigned short)((j << 8) | k);
    return t;
}
__constant__ PairTab PT = make_tab();

__global__ __launch_bounds__(128) void fchl_kernel(
    const float* __restrict__ X,      // [B][MAXN][3]
    const float* __restrict__ Z,      // [B][MAXN]
    const int* __restrict__ counts,   // [B]
    float* __restrict__ out)          // [B][MAXN][OUT_LEN]
{
    const int i = blockIdx.x;      // atom index within molecule
    const int b = blockIdx.y;      // molecule
    const int tid = threadIdx.x;
    const int cnt = counts[b];

    __shared__ float sx[MAXN], sy[MAXN], szc[MAXN];
    __shared__ int   s_win[MAXN];
    __shared__ float s_r[MAXN], s_fc[MAXN], s_mu[MAXN], s_i2ln[MAXN], s_pref[MAXN];
    __shared__ int   sspec[MAXN];
    __shared__ int   cntP[NPAIR], curP[NPAIR];
    __shared__ int   cntSp[NSPEC];
    __shared__ int   spList[NSPEC][MAXN];
    __shared__ float4 s_pair[NCOMB];
    __shared__ float s_out[OUT_LEN];     // staged output row (coalesced write at end)

    float* orow = out + (size_t)(b * MAXN + i) * OUT_LEN;

    // ---- P1: zero counters + per-neighbor-j quantities + species lists ----
    if (tid >= 28 && tid < 28 + NSPEC) cntSp[tid - 28] = 0;            // wave 0, before its atomics
    if (tid >= 64 && tid < 64 + NPAIR) { cntP[tid - 64] = 0; curP[tid - 64] = 0; }  // wave 1
    if (tid < MAXN) {
        const int j = tid;
        // broadcast loads of atom i's coords (same addr all lanes, L1/L2-cached)
        float xi = X[(b * MAXN + i) * 3 + 0];
        float yi = X[(b * MAXN + i) * 3 + 1];
        float zi = X[(b * MAXN + i) * 3 + 2];
        float xj = X[(b * MAXN + j) * 3 + 0];
        float yj = X[(b * MAXN + j) * 3 + 1];
        float zj = X[(b * MAXN + j) * 3 + 2];
        sx[j] = xj; sy[j] = yj; szc[j] = zj;
        float z = Z[b * MAXN + j];
        int s = -1;
        if (z == 1.0f) s = 0;
        else if (z == 6.0f) s = 1;
        else if (z == 7.0f) s = 2;
        else if (z == 8.0f) s = 3;
        sspec[j] = s;

        float dx = xi - xj, dy = yi - yj, dz = zi - zj;
        float r = sqrtf(dx * dx + dy * dy + dz * dz);
        bool w = (i < cnt) && (j < cnt) && (j != i) && (r < RCUT);
        s_win[j] = w ? 1 : 0;
        if (w) {
            // fc = 0.5*(cos(pi*r/8)+1) = 0.5*(cos(2pi * r/16)+1)
            float fc = 0.5f * (hcos_rev(r * (1.0f / 16.0f)) + 1.0f);
            float ln = LN2F * hlog2(1.0f + ETA2 * hrcp(r * r));
            float lr = LN2F * hlog2(r);
            s_r[j] = r;
            s_fc[j] = fc;
            s_mu[j] = lr - 0.5f * ln;
            s_i2ln[j] = LOG2E / (2.0f * ln);
            s_pref[j] = fc * hexp2(-1.8f * hlog2(r)) * hrsq(ln);  // fc*r^-1.8/sqrt(ln)
            int pos = atomicAdd(&cntSp[s], 1);                    // same-wave after zeroing
            spList[s][pos] = j;
        } else {
            s_r[j] = 1.0f; s_fc[j] = 0.0f; s_mu[j] = 0.0f;
            s_i2ln[j] = 1.0f; s_pref[j] = 0.0f;
        }
    }
    __syncthreads();   // bar A

    // ---- P2: fused histogram + geometry into registers (<=3 combos/thread) ----
    float avgv[3], w0v[3], w1v[3];
    int   tagv[3];
    #pragma unroll
    for (int p = 0; p < 3; ++p) {
        int idx = tid + p * 128;
        int tg = -1; float av = 0.f, a0 = 0.f, a1 = 0.f;
        if (idx < NCOMB) {
            int jk = PT.jk[idx];
            int j = jk >> 8, k = jk & 255;
            if (s_win[j] && s_win[k]) {
                float rij = s_r[j], rik = s_r[k];
                float dx = sx[j] - sx[k], dy = sy[j] - sy[k], dz = szc[j] - szc[k];
                float rjk = sqrtf(dx * dx + dy * dy + dz * dz);

                float rij2 = rij * rij, rik2 = rik * rik, rjk2 = rjk * rjk;
                float cos_i = (rij2 + rik2 - rjk2) * 0.5f * hrcp(rij * rik);
                float cos_j = (rij2 + rjk2 - rik2) * 0.5f * hrcp(rij * rjk);
                float cos_k = (rik2 + rjk2 - rij2) * 0.5f * hrcp(rik * rjk);

                float atm = (1.0f + 3.0f * cos_i * cos_j * cos_k)
                            * hexp2(-0.57f * hlog2(rij * rik * rjk));
                float w = W3 * atm * s_fc[j] * s_fc[k];

                float c = fminf(fmaxf(cos_i, -1.0f), 1.0f);
                float sn = sqrtf(fminf(fmaxf(1.0f - c * c, 1e-12f), 1.0f));

                int pj = sspec[j], pk = sspec[k];
                int pp = min(pj, pk), q = max(pj, pk);
                tg = pp * NSPEC - (pp * (pp - 1)) / 2 + (q - pp);
                atomicAdd(&cntP[tg], 1);
                av = 0.5f * (rij + rik);
                a0 = 2.0f * c * w;
                a1 = 2.0f * sn * w;
            }
        }
        tagv[p] = tg; avgv[p] = av; w0v[p] = a0; w1v[p] = a1;
    }
    __syncthreads();   // bar B

    // ---- P3: scatter register combos into P-sorted LDS (inline predicated base) ----
    #pragma unroll
    for (int p = 0; p < 3; ++p) {
        int tg = tagv[p];
        if (tg >= 0) {
            int bs = 0;
            #pragma unroll
            for (int q = 0; q < NPAIR - 1; ++q) bs += (q < tg) ? cntP[q] : 0;
            int slot = bs + atomicAdd(&curP[tg], 1);
            s_pair[slot] = make_float4(avgv[p], w0v[p], w1v[p], 0.0f);
        }
    }
    __syncthreads();   // bar C

    // ---- P4: unified tail — 200 gather bins + 96 two-body, results to LDS ----
    for (int t = tid; t < NTASK; t += 128) {
        if (t < NPAIR * NRS3) {
            const int P = t / NRS3;
            const int l = t % NRS3;
            const float rs = 0.4f * (float)(l + 1);
            int s0 = 0;
            #pragma unroll
            for (int q = 0; q < NPAIR - 1; ++q) s0 += (q < P) ? cntP[q] : 0;
            const int s1 = s0 + cntP[P];
            float acc0 = 0.0f, acc1 = 0.0f;
            for (int s = s0; s < s1; ++s) {
                float4 pd = s_pair[s];
                float dd = pd.x - rs;
                float e = hexp2(-(ETA3 * LOG2E) * dd * dd);
                acc0 += pd.y * e;
                acc1 += pd.z * e;
            }
            s_out[REP2_LEN + P * (NRS3 * 2) + l * 2 + 0] = acc0;
            s_out[REP2_LEN + P * (NRS3 * 2) + l * 2 + 1] = acc1;
        } else {
            const int t2 = t - NPAIR * NRS3;       // 0..95
            const int sp = t2 / NRS2;
            const int m = t2 % NRS2;
            const float rs2 = (float)(m + 1) * (8.0f / 24.0f);
            const float lrs2 = LN2F * hlog2(rs2);
            const float nrm = 0.3989422804014327f / rs2;   // 1/(sqrt(2pi)*rs2)
            float acc = 0.0f;
            const int n = cntSp[sp];
            for (int c = 0; c < n; ++c) {
                int j = spList[sp][c];
                float d = lrs2 - s_mu[j];
                acc += s_pref[j] * hexp2(-d * d * s_i2ln[j]);
            }
            s_out[sp * NRS2 + m] = acc * nrm;
        }
    }
    __syncthreads();   // bar D

    // ---- P5: coalesced row write — 124 full float4 stores (full 64B lines) ----
    if (tid < OUT_LEN / 4) {
        reinterpret_cast<float4*>(orow)[tid] =
            reinterpret_cast<const float4*>(s_out)[tid];
    }
}

extern "C" void kernel_launch(void* const* d_in, const int* in_sizes, int n_in,
                              void* d_out, int out_size, void* d_ws, size_t ws_size,
                              hipStream_t stream) {
    const float* X = (const float*)d_in[0];
    const float* Z = (const float*)d_in[1];
    // d_in[2] = atomIDs, d_in[3] = molIDs (unused by reference math)
    const int* counts = (const int*)d_in[4];
    float* out = (float*)d_out;

    dim3 grid(MAXN, B_MOL);   // one block per (atom i, molecule b)
    dim3 block(128);
    hipLaunchKernelGGL(fchl_kernel, grid, block, 0, stream, X, Z, counts, out);
}

// Round 8
// 18.055 us; speedup vs baseline: 2.6817x; 1.1980x over previous
//
#include <hip/hip_runtime.h>

#define B_MOL 64
#define MAXN 28
#define NSPEC 4
#define NRS2 24
#define NRS3 20
#define NPAIR 10
#define NCOMB 378                       // 28*27/2 fixed (j<k) combos
#define SPAIR_CAP 408                   // 378 + 10 buckets * 3 pad
#define REP2_LEN (NSPEC * NRS2)         // 96
#define REP3_LEN (NPAIR * NRS3 * 2)     // 400
#define OUT_LEN (REP2_LEN + REP3_LEN)   // 496
#define NBIN3 (NPAIR * NRS3)            // 200
#define RCUT 8.0f
#define ETA2 0.32f
#define ETA3 2.7f
#define LOG2E 1.4426950408889634f
#define LN2F 0.6931471805599453f
// sqrt(2.7/pi)*13.4 computed in double, cast to f32
#define W3 12.4225783348083f

#define PAD4(c) (((c) + 3) & ~3)

// hardware transcendentals (raw gfx950 instructions, no libm namespace)
__device__ __forceinline__ float hexp2(float x) { return __builtin_amdgcn_exp2f(x); }
__device__ __forceinline__ float hlog2(float x) { return __builtin_amdgcn_logf(x); }
__device__ __forceinline__ float hrcp(float x)  { return __builtin_amdgcn_rcpf(x); }
__device__ __forceinline__ float hrsq(float x)  { return __builtin_amdgcn_rsqf(x); }
// cos(2*pi*t), t in revolutions
__device__ __forceinline__ float hcos_rev(float t) { return __builtin_amdgcn_cosf(t); }

// compile-time (j,k) pair table, j<k<28, packed (j<<8)|k
struct PairTab { unsigned short jk[NCOMB]; };
static constexpr PairTab make_tab() {
    PairTab t{};
    int idx = 0;
    for (int j = 0; j < MAXN; ++j)
        for (int k = j + 1; k < MAXN; ++k)
            t.jk[idx++] = (unsigned short)((j << 8) | k);
    return t;
}
__constant__ PairTab PT = make_tab();

__global__ __launch_bounds__(256) void fchl_kernel(
    const float* __restrict__ X,      // [B][MAXN][3]
    const float* __restrict__ Z,      // [B][MAXN]
    const int* __restrict__ counts,   // [B]
    float* __restrict__ out)          // [B][MAXN][OUT_LEN]
{
    const int i = blockIdx.x;      // atom index within molecule
    const int b = blockIdx.y;      // molecule
    const int tid = threadIdx.x;
    const int cnt = counts[b];

    __shared__ float sx[MAXN], sy[MAXN], szc[MAXN];
    __shared__ int   s_win[MAXN];
    __shared__ float s_r[MAXN], s_fc[MAXN];
    __shared__ float s_mu[MAXN + 1], s_i2ln[MAXN + 1], s_pref[MAXN + 1];  // [28] = dummy
    __shared__ int   sspec[MAXN];
    __shared__ int   cntP[NPAIR], curP[NPAIR];
    __shared__ int   cntSp[NSPEC];
    __shared__ int   spList[NSPEC][32];          // 32 cap so padded reads stay in-row
    __shared__ signed char s_tag[NCOMB];
    __shared__ float4 s_pair[SPAIR_CAP];

    float* orow = out + (size_t)(b * MAXN + i) * OUT_LEN;

    // ---- P1: zero s_pair + counters, per-neighbor-j quantities, species lists ----
    {
        const float4 z4 = make_float4(0.f, 0.f, 0.f, 0.f);
        for (int t = tid; t < SPAIR_CAP; t += 256) s_pair[t] = z4;   // padding slots stay 0
    }
    if (tid >= 28 && tid < 28 + NSPEC) cntSp[tid - 28] = 0;        // wave 0, program-order before its atomics
    if (tid >= 64 && tid < 64 + NPAIR) { cntP[tid - 64] = 0; curP[tid - 64] = 0; }  // wave 1
    if (tid == MAXN) { s_pref[MAXN] = 0.f; s_mu[MAXN] = 0.f; s_i2ln[MAXN] = 1.f; }  // dummy atom
    if (tid < MAXN) {
        const int j = tid;
        float xi = X[(b * MAXN + i) * 3 + 0];   // broadcast loads
        float yi = X[(b * MAXN + i) * 3 + 1];
        float zi = X[(b * MAXN + i) * 3 + 2];
        float xj = X[(b * MAXN + j) * 3 + 0];
        float yj = X[(b * MAXN + j) * 3 + 1];
        float zj = X[(b * MAXN + j) * 3 + 2];
        sx[j] = xj; sy[j] = yj; szc[j] = zj;
        float z = Z[b * MAXN + j];
        int s = -1;
        if (z == 1.0f) s = 0;
        else if (z == 6.0f) s = 1;
        else if (z == 7.0f) s = 2;
        else if (z == 8.0f) s = 3;
        sspec[j] = s;

        float dx = xi - xj, dy = yi - yj, dz = zi - zj;
        float r = sqrtf(dx * dx + dy * dy + dz * dz);
        bool w = (i < cnt) && (j < cnt) && (j != i) && (r < RCUT);
        s_win[j] = w ? 1 : 0;
        if (w) {
            // fc = 0.5*(cos(pi*r/8)+1) = 0.5*(cos(2pi * r/16)+1)
            float fc = 0.5f * (hcos_rev(r * (1.0f / 16.0f)) + 1.0f);
            float ln = LN2F * hlog2(1.0f + ETA2 * hrcp(r * r));
            float lr = LN2F * hlog2(r);
            s_r[j] = r;
            s_fc[j] = fc;
            s_mu[j] = lr - 0.5f * ln;
            s_i2ln[j] = LOG2E / (2.0f * ln);
            s_pref[j] = fc * hexp2(-1.8f * hlog2(r)) * hrsq(ln);  // fc*r^-1.8/sqrt(ln)
            int pos = atomicAdd(&cntSp[s], 1);                    // same-wave, after zeroing above
            spList[s][pos] = j;
        } else {
            s_r[j] = 1.0f; s_fc[j] = 0.0f; s_mu[j] = 0.0f;
            s_i2ln[j] = 1.0f; s_pref[j] = 0.0f;
        }
    }
    __syncthreads();   // bar A

    // ---- P2a: cheap histogram + tag cache (no geometry) ----
    for (int idx = tid; idx < NCOMB; idx += 256) {
        int jk = PT.jk[idx];
        int j = jk >> 8, k = jk & 255;
        int tg = -1;
        if (s_win[j] && s_win[k]) {
            int pj = sspec[j], pk = sspec[k];
            int pp = min(pj, pk), q = max(pj, pk);
            tg = pp * NSPEC - (pp * (pp - 1)) / 2 + (q - pp);
            atomicAdd(&cntP[tg], 1);
        }
        s_tag[idx] = (signed char)tg;
    }
    __syncthreads();   // bar B

    // ---- P2b: geometry + direct sorted scatter (padded bucket bases) ----
    for (int idx = tid; idx < NCOMB; idx += 256) {
        int tg = s_tag[idx];
        if (tg < 0) continue;
        int jk = PT.jk[idx];
        int j = jk >> 8, k = jk & 255;

        float rij = s_r[j], rik = s_r[k];
        float dx = sx[j] - sx[k], dy = sy[j] - sy[k], dz = szc[j] - szc[k];
        float rjk = sqrtf(dx * dx + dy * dy + dz * dz);

        float rij2 = rij * rij, rik2 = rik * rik, rjk2 = rjk * rjk;
        float cos_i = (rij2 + rik2 - rjk2) * 0.5f * hrcp(rij * rik);
        float cos_j = (rij2 + rjk2 - rik2) * 0.5f * hrcp(rij * rjk);
        float cos_k = (rik2 + rjk2 - rij2) * 0.5f * hrcp(rik * rjk);

        float atm = (1.0f + 3.0f * cos_i * cos_j * cos_k)
                    * hexp2(-0.57f * hlog2(rij * rik * rjk));
        float w = W3 * atm * s_fc[j] * s_fc[k];

        float c = fminf(fmaxf(cos_i, -1.0f), 1.0f);
        float sn = sqrtf(fminf(fmaxf(1.0f - c * c, 1e-12f), 1.0f));

        int bs = 0;
        #pragma unroll
        for (int q = 0; q < NPAIR - 1; ++q) bs += (q < tg) ? PAD4(cntP[q]) : 0;
        int slot = bs + atomicAdd(&curP[tg], 1);
        s_pair[slot] = make_float4(0.5f * (rij + rik), 2.0f * c * w, 2.0f * sn * w, 0.0f);
    }
    __syncthreads();   // bar C

    // ---- tail: tids 0-199 gather bins (unroll-4, padded trip);
    //            tids 200-255 two-body (<=2 rounds, unroll-4 w/ dummy idx) ----
    if (tid < NBIN3) {
        const int P = tid / NRS3;
        const int l = tid % NRS3;
        const float rs = 0.4f * (float)(l + 1);
        int s0 = 0;
        #pragma unroll
        for (int q = 0; q < NPAIR - 1; ++q) s0 += (q < P) ? PAD4(cntP[q]) : 0;
        const int trip = PAD4(cntP[P]);
        float acc0 = 0.0f, acc1 = 0.0f;
        for (int s = s0; s < s0 + trip; s += 4) {
            float4 p0 = s_pair[s + 0];
            float4 p1 = s_pair[s + 1];
            float4 p2 = s_pair[s + 2];
            float4 p3 = s_pair[s + 3];
            float d0 = p0.x - rs, d1 = p1.x - rs, d2 = p2.x - rs, d3 = p3.x - rs;
            float e0 = hexp2(-(ETA3 * LOG2E) * d0 * d0);
            float e1 = hexp2(-(ETA3 * LOG2E) * d1 * d1);
            float e2 = hexp2(-(ETA3 * LOG2E) * d2 * d2);
            float e3 = hexp2(-(ETA3 * LOG2E) * d3 * d3);
            acc0 += p0.y * e0 + p1.y * e1 + p2.y * e2 + p3.y * e3;
            acc1 += p0.z * e0 + p1.z * e1 + p2.z * e2 + p3.z * e3;
        }
        orow[REP2_LEN + P * (NRS3 * 2) + l * 2 + 0] = acc0;
        orow[REP2_LEN + P * (NRS3 * 2) + l * 2 + 1] = acc1;
    } else {
        for (int t2 = tid - 200; t2 < REP2_LEN; t2 += 56) {
            const int sp = t2 / NRS2;
            const int m = t2 % NRS2;
            const float rs2 = (float)(m + 1) * (8.0f / 24.0f);
            const float lrs2 = LN2F * hlog2(rs2);
            const float nrm = 0.3989422804014327f / rs2;   // 1/(sqrt(2pi)*rs2)
            const int n = cntSp[sp];
            const int trip = PAD4(n);
            float acc = 0.0f;
            for (int c = 0; c < trip; c += 4) {
                int r0 = spList[sp][c + 0];
                int r1 = spList[sp][c + 1];
                int r2 = spList[sp][c + 2];
                int r3 = spList[sp][c + 3];
                int j0 = (c + 0 < n) ? r0 : MAXN;    // select before address use
                int j1 = (c + 1 < n) ? r1 : MAXN;
                int j2 = (c + 2 < n) ? r2 : MAXN;
                int j3 = (c + 3 < n) ? r3 : MAXN;
                float d0 = lrs2 - s_mu[j0], d1 = lrs2 - s_mu[j1];
                float d2 = lrs2 - s_mu[j2], d3 = lrs2 - s_mu[j3];
                acc += s_pref[j0] * hexp2(-d0 * d0 * s_i2ln[j0])
                     + s_pref[j1] * hexp2(-d1 * d1 * s_i2ln[j1])
                     + s_pref[j2] * hexp2(-d2 * d2 * s_i2ln[j2])
                     + s_pref[j3] * hexp2(-d3 * d3 * s_i2ln[j3]);
            }
            orow[sp * NRS2 + m] = acc * nrm;
        }
    }
}

extern "C" void kernel_launch(void* const* d_in, const int* in_sizes, int n_in,
                              void* d_out, int out_size, void* d_ws, size_t ws_size,
                              hipStream_t stream) {
    const float* X = (const float*)d_in[0];
    const float* Z = (const float*)d_in[1];
    // d_in[2] = atomIDs, d_in[3] = molIDs (unused by reference math)
    const int* counts = (const int*)d_in[4];
    float* out = (float*)d_out;

    dim3 grid(MAXN, B_MOL);   // one block per (atom i, molecule b)
    dim3 block(256);
    hipLaunchKernelGGL(fchl_kernel, grid, block, 0, stream, X, Z, counts, out);
}